// Round 1
// baseline (18.552 us; speedup 1.0000x reference)
//
#include <hip/hip_runtime.h>
#include <math.h>

// LocalPODLoss: out = 0.5 * (1e-6 + sqrt(ss)), where ss decomposes per
// (b,c) 32x32 tile of D = new - old into triangular-weighted squares of
// 16-long sliding-window sums along rows (left term) and cols (right term).
// Only scale s=1 contributes (s=0 has zero window positions).

#define TILES_PER_BLOCK 8
#define TILE_STRIDE (32 * 33)  // padded LDS tile (33-word rows: conflict-free column reads)

__global__ __launch_bounds__(256) void pod_partial(const float* __restrict__ nf,
                                                   const float* __restrict__ of,
                                                   float* __restrict__ partial) {
    __shared__ float ds[TILES_PER_BLOCK * TILE_STRIDE];
    const int tid = threadIdx.x;
    const size_t base = (size_t)blockIdx.x * (TILES_PER_BLOCK * 1024);

    // Load 8 tiles (8192 floats) of new/old via float4, compute D, stage in LDS.
    const float4* nf4 = reinterpret_cast<const float4*>(nf + base);
    const float4* of4 = reinterpret_cast<const float4*>(of + base);
#pragma unroll
    for (int it = 0; it < (TILES_PER_BLOCK * 1024) / (256 * 4); ++it) {
        int e4 = it * 256 + tid;   // float4 index within this block's chunk
        float4 a = nf4[e4];
        float4 b = of4[e4];
        int e = e4 * 4;            // flat float index (no row crossing: 32 % 4 == 0)
        int tile = e >> 10;
        int r = (e >> 5) & 31;
        int c = e & 31;
        float* dst = &ds[tile * TILE_STRIDE + r * 33 + c];
        dst[0] = a.x - b.x;
        dst[1] = a.y - b.y;
        dst[2] = a.z - b.z;
        dst[3] = a.w - b.w;
    }
    __syncthreads();

    float acc = 0.0f;

    // Phase A (left term): thread owns (tile, col). 16-window sliding sum over rows.
    {
        int tile = tid >> 5, col = tid & 31;
        const float* colp = &ds[tile * TILE_STRIDE + col];
        float v[32];
#pragma unroll
        for (int r = 0; r < 32; ++r) v[r] = colp[r * 33];
        float W = 0.0f;
#pragma unroll
        for (int r = 0; r < 16; ++r) W += v[r];
        float s2 = W * W;
#pragma unroll
        for (int i = 1; i < 16; ++i) { W += v[i + 15] - v[i - 1]; s2 += W * W; }
        float wl = (col < 16) ? (float)(col + 1) : (float)(31 - col);  // triangular cnt, 0 at col=31
        acc += wl * s2;
    }

    // Phase B (right term): thread owns (tile, row). 16-window sliding sum over cols.
    {
        int tile = tid >> 5, row = tid & 31;
        const float* rowp = &ds[tile * TILE_STRIDE + row * 33];
        float v[32];
#pragma unroll
        for (int c = 0; c < 32; ++c) v[c] = rowp[c];
        float W = 0.0f;
#pragma unroll
        for (int c = 0; c < 16; ++c) W += v[c];
        float s2 = W * W;
#pragma unroll
        for (int j = 1; j < 16; ++j) { W += v[j + 15] - v[j - 1]; s2 += W * W; }
        float wr = (row < 16) ? (float)(row + 1) : (float)(31 - row);
        acc += wr * s2;
    }

    acc *= (1.0f / 256.0f);  // the /w and /h squared

    // Deterministic block reduction: wave64 shuffle + LDS combine.
#pragma unroll
    for (int off = 32; off > 0; off >>= 1) acc += __shfl_down(acc, off, 64);
    __shared__ float wsum[4];
    if ((tid & 63) == 0) wsum[tid >> 6] = acc;
    __syncthreads();
    if (tid == 0) partial[blockIdx.x] = (wsum[0] + wsum[1]) + (wsum[2] + wsum[3]);
}

__global__ __launch_bounds__(256) void pod_final(const float* __restrict__ partial, int n,
                                                 float* __restrict__ out) {
    __shared__ float sh[256];
    int tid = threadIdx.x;
    float a = 0.0f;
    for (int i = tid; i < n; i += 256) a += partial[i];  // fixed order: deterministic
    sh[tid] = a;
    __syncthreads();
    for (int s = 128; s > 0; s >>= 1) {
        if (tid < s) sh[tid] += sh[tid + s];
        __syncthreads();
    }
    if (tid == 0) out[0] = 0.5f * (1e-6f + sqrtf(sh[0]));
}

extern "C" void kernel_launch(void* const* d_in, const int* in_sizes, int n_in,
                              void* d_out, int out_size, void* d_ws, size_t ws_size,
                              hipStream_t stream) {
    const float* nf = (const float*)d_in[0];
    const float* of = (const float*)d_in[1];
    float* out = (float*)d_out;
    float* partial = (float*)d_ws;  // 1024 floats = 4 KB

    const int ntiles = 16 * 512;                      // B * C
    const int nblocks = ntiles / TILES_PER_BLOCK;     // 1024

    hipLaunchKernelGGL(pod_partial, dim3(nblocks), dim3(256), 0, stream, nf, of, partial);
    hipLaunchKernelGGL(pod_final, dim3(1), dim3(256), 0, stream, partial, nblocks, out);
}